// Round 7
// baseline (345.436 us; speedup 1.0000x reference)
//
#include <hip/hip_runtime.h>
#include <hip/hip_bf16.h>
#include <math.h>

#define N_ATOMS 8192
#define B_BATCH 64
#define E_EDGES 262144
#define S_SPEC 4
#define NMAX 8
#define PS_DIM 4096
#define PS_K 2304            // folded upper-tri K: 528 pairs*4 lb = 2112, pad to 9*256
#define H1_DIM 1024
#define CAP4 48
#define CUTR 5.0f
#define PI_F 3.14159265358979f

typedef __bf16 bf16;
typedef bf16 bf16x8 __attribute__((ext_vector_type(8)));
typedef float floatx4 __attribute__((ext_vector_type(4)));
typedef int intx8 __attribute__((ext_vector_type(8)));
typedef unsigned char u8;

// async global->LDS, 16B per lane; LDS dest = wave-uniform base + lane*16
__device__ __forceinline__ void g2lds16(const void* g, void* l) {
    __builtin_amdgcn_global_load_lds(
        (const __attribute__((address_space(1))) void*)g,
        (__attribute__((address_space(3))) void*)l, 16, 0, 0);
}

__device__ __forceinline__ int pk_fp8x4(float a, float b, float c, float d) {
    int lo = __builtin_amdgcn_cvt_pk_fp8_f32(a, b, 0, false);
    return __builtin_amdgcn_cvt_pk_fp8_f32(c, d, lo, true);
}

// ------------------------------------------------- merged prep (1 dispatch):
// blocks [0,1024): edge scatter (block 0 also zeroes out[])
// blocks [1024,1024+2304): W1 gamma-fold -> Wt1 fp8 + b1 accumulation
// blocks [1024+2304, 1024+3328): W2 transpose -> Wt2 fp8
__global__ __launch_bounds__(256) void prep_kernel(
    const float* __restrict__ pos, const float* __restrict__ cells,
    const int* __restrict__ numbers, const int* __restrict__ ei,
    const float* __restrict__ eo, const int* __restrict__ batch,
    int* __restrict__ cnt, float4* __restrict__ bucket,
    const float* __restrict__ W1, const float* __restrict__ gamma,
    const float* __restrict__ beta, const float* __restrict__ W2,
    u8* __restrict__ Wt1, u8* __restrict__ Wt2, float* __restrict__ b1,
    float* __restrict__ out)
{
    if (blockIdx.x < 1024) {
        // ---------------- scatter ----------------
        if (blockIdx.x == 0 && threadIdx.x < B_BATCH) out[threadIdx.x] = 0.0f;
        int e = blockIdx.x * 256 + threadIdx.x;
        int i = ei[e];
        int j = ei[E_EDGES + e];
        int b = batch[i];
        const float* cell = cells + b * 9;
        float o0 = eo[e * 3 + 0], o1 = eo[e * 3 + 1], o2 = eo[e * 3 + 2];
        float rv[3];
        #pragma unroll
        for (int d = 0; d < 3; ++d) {
            float shift = o0 * cell[0 * 3 + d] + o1 * cell[1 * 3 + d] + o2 * cell[2 * 3 + d];
            rv[d] = pos[j * 3 + d] - pos[i * 3 + d] + shift;
        }
        float r2 = rv[0] * rv[0] + rv[1] * rv[1] + rv[2] * rv[2] + 1e-12f;
        if (r2 >= CUTR * CUTR) return;   // fc == 0 -> zero contribution
        float r = sqrtf(r2);
        float a1 = r * (PI_F / CUTR);
        int sp = numbers[j];
        int q = i * S_SPEC + sp;
        int slot = atomicAdd(&cnt[q], 1);
        if (slot < CAP4)
            bucket[q * CAP4 + slot] = make_float4(rv[0], rv[1], rv[2], a1);
        return;
    }

    // ---------------- weight prep ----------------
    __shared__ float tbuf[32][33];
    __shared__ float bred[8][32];
    int wid = blockIdx.x - 1024;
    int by = wid & 31;          // n-tile [0,32)
    int bx = wid >> 5;          // k-tile [0,104)
    int tx = threadIdx.x & 31, ty = threadIdx.x >> 5;
    int n0 = by * 32;

    if (bx < 72) {
        int k0 = bx * 32;
        float bacc = 0.0f;
        for (int r = 0; r < 32; r += 8) {
            int kk = ty + r;
            int kp = k0 + kk;
            int u = kp >> 2, lb = kp & 3;
            float val = 0.0f;
            if (u < 528) {
                int x = 0;
                while ((x + 1) * (64 - x) / 2 <= u) ++x;
                int y = x + (u - x * (65 - x) / 2);
                int p1 = x * 128 + y * 4 + lb;
                float w1v = W1[(size_t)p1 * H1_DIM + n0 + tx];
                val = gamma[p1] * w1v;
                bacc += beta[p1] * w1v;
                if (x < y) {
                    int p2 = y * 128 + x * 4 + lb;
                    float w2v = W1[(size_t)p2 * H1_DIM + n0 + tx];
                    val += gamma[p2] * w2v;
                    bacc += beta[p2] * w2v;
                }
            }
            tbuf[kk][tx] = val;
        }
        bred[ty][tx] = bacc;
        __syncthreads();
        if (ty == 0) {
            float s = 0.0f;
            #pragma unroll
            for (int i = 0; i < 8; ++i) s += bred[i][tx];
            atomicAdd(&b1[n0 + tx], s);
        }
        if (threadIdx.x < 64) {
            int nl = threadIdx.x >> 1, cc = threadIdx.x & 1;
            int n = n0 + nl;
            unsigned int w[4];
            #pragma unroll
            for (int g = 0; g < 4; ++g) {
                int kb = cc * 16 + g * 4;
                w[g] = (unsigned int)pk_fp8x4(
                    tbuf[kb + 0][nl] * 64.0f, tbuf[kb + 1][nl] * 64.0f,
                    tbuf[kb + 2][nl] * 64.0f, tbuf[kb + 3][nl] * 64.0f);
            }
            int gc = (k0 >> 4) + cc;
            int gcs = (gc & ~7) | ((gc & 7) ^ (n & 7));
            *(uint4*)(Wt1 + (size_t)n * PS_K + (size_t)gcs * 16) =
                make_uint4(w[0], w[1], w[2], w[3]);
        }
    } else {
        int k0 = (bx - 72) * 32;
        #pragma unroll
        for (int r = 0; r < 32; r += 8)
            tbuf[ty + r][tx] = W2[(size_t)(k0 + ty + r) * H1_DIM + n0 + tx];
        __syncthreads();
        if (threadIdx.x < 64) {
            int nl = threadIdx.x >> 1, cc = threadIdx.x & 1;
            int n = n0 + nl;
            unsigned int w[4];
            #pragma unroll
            for (int g = 0; g < 4; ++g) {
                int kb = cc * 16 + g * 4;
                w[g] = (unsigned int)pk_fp8x4(
                    tbuf[kb + 0][nl] * 32.0f, tbuf[kb + 1][nl] * 32.0f,
                    tbuf[kb + 2][nl] * 32.0f, tbuf[kb + 3][nl] * 32.0f);
            }
            int gc = (k0 >> 4) + cc;
            int gcs = (gc & ~7) | ((gc & 7) ^ (n & 7));
            *(uint4*)(Wt2 + (size_t)n * H1_DIM + (size_t)gcs * 16) =
                make_uint4(w[0], w[1], w[2], w[3]);
        }
    }
}

// ---------------------------------------------------------------- fused accum + PS/LN
// RESTRUCTURED: wave-per-atom end-to-end, ZERO barriers. Wave w owns atom
// blockIdx*4+w: Phase A writes cl[w] (same-wave LDS ordering via lgkmcnt),
// Phase B stats via 64-lane shfl_xor reduce, ps values held in registers
// (float4 psq[16], fully unrolled), per-wave ps_s8 staging + psn store.
// *** DIAGNOSTIC: x3 rep (idempotent) for top-5 visibility; true = dur/3.
// REMOVE rep next round. ***
__global__ __launch_bounds__(256) void accum_ps_kernel(
    const float4* __restrict__ bucket, const int* __restrict__ cnt,
    const float* __restrict__ gamma, const float* __restrict__ beta,
    const float* __restrict__ Wps, u8* __restrict__ psn, float* __restrict__ psl)
{
    __shared__ __align__(16) float cl[4][32 * 20];   // [wave][x*20+m], ld=20
    __shared__ __align__(16) u8 ps_s8[4][PS_K];      // per-wave staging

    int t = threadIdx.x;
    int wv = t >> 6, lane = t & 63;
    int atom = blockIdx.x * 4 + wv;

    for (int rep = 0; rep < 3; ++rep) {
        // ---------------- Phase A (per-wave) ----------------
        {
            int sp_l = lane >> 4;
            int nidx = (lane >> 1) & 7;
            float nf = (float)(nidx + 1);
            int par = lane & 1;

            int myCnt = cnt[atom * S_SPEC + sp_l];
            if (myCnt > CAP4) myCnt = CAP4;
            int m1 = max(myCnt, __shfl_xor(myCnt, 16));
            int mx = max(m1, __shfl_xor(m1, 32));

            const float4* q = bucket + (size_t)(atom * S_SPEC + sp_l) * CAP4;
            float acc[8] = {};
            #pragma unroll 2
            for (int e = 0; e < mx; ++e) {
                float4 d = q[e];
                bool valid = e < myCnt;
                float a1 = d.w;
                float inv_r = (PI_F / CUTR) * __frcp_rn(a1);
                float fc = 0.5f * __cosf(a1) + 0.5f;
                float rn = fc * inv_r * __sinf(nf * a1);
                rn = valid ? rn : 0.0f;

                float x = d.x * inv_r, y = d.y * inv_r, z = d.z * inv_r;
                float x2 = x * x, y2 = y * y, z2 = z * z;
                float Ys[8];
                if (par == 0) {
                    Ys[0] = 0.28209479f;
                    Ys[1] = 0.48860251f * y;
                    Ys[2] = 0.48860251f * z;
                    Ys[3] = 0.48860251f * x;
                    Ys[4] = 1.09254843f * x * y;
                    Ys[5] = 1.09254843f * y * z;
                    Ys[6] = 0.31539157f * (3.0f * z2 - 1.0f);
                    Ys[7] = 1.09254843f * x * z;
                } else {
                    Ys[0] = 0.54627422f * (x2 - y2);
                    Ys[1] = 0.59004359f * y * (3.0f * x2 - y2);
                    Ys[2] = 2.89061144f * x * y * z;
                    Ys[3] = 0.45704579f * y * (5.0f * z2 - 1.0f);
                    Ys[4] = 0.37317633f * z * (5.0f * z2 - 3.0f);
                    Ys[5] = 0.45704579f * x * (5.0f * z2 - 1.0f);
                    Ys[6] = 1.44530572f * z * (x2 - y2);
                    Ys[7] = 0.59004359f * x * (x2 - 3.0f * y2);
                }
                #pragma unroll
                for (int k = 0; k < 8; ++k) acc[k] += rn * Ys[k];
            }
            int X = sp_l * 8 + nidx;
            float* dst = &cl[wv][X * 20 + par * 8];
            *(float4*)(dst + 0) = make_float4(acc[0], acc[1], acc[2], acc[3]);
            *(float4*)(dst + 4) = make_float4(acc[4], acc[5], acc[6], acc[7]);
        }
        if (lane < 48) ((int*)ps_s8[wv])[528 + lane] = 0;   // zero K-pad words
        // no barrier: same wave produces and consumes cl[wv] / ps_s8[wv]

        // ---------------- Phase B (wave-local) ----------------
        {
            const float* cl_x = cl[wv];
            int y = lane & 31;
            int xb = lane >> 5;
            float4 cya = *(const float4*)&cl_x[y * 20 + 0];
            float4 cyb = *(const float4*)&cl_x[y * 20 + 4];
            float4 cyc = *(const float4*)&cl_x[y * 20 + 8];
            float4 cyd = *(const float4*)&cl_x[y * 20 + 12];

            float4 psq[16];
            float sum = 0.0f, sumsq = 0.0f;
            #pragma unroll
            for (int q = 0; q < 16; ++q) {
                int x = xb + 2 * q;
                float4 xa = *(const float4*)&cl_x[x * 20 + 0];
                float4 xbv = *(const float4*)&cl_x[x * 20 + 4];
                float4 xc = *(const float4*)&cl_x[x * 20 + 8];
                float4 xd = *(const float4*)&cl_x[x * 20 + 12];
                float s0 = xa.x * cya.x;
                float s1 = xa.y * cya.y + xa.z * cya.z + xa.w * cya.w;
                float s2 = xbv.x * cyb.x + xbv.y * cyb.y + xbv.z * cyb.z + xbv.w * cyb.w
                         + xc.x * cyc.x;
                float s3 = xc.y * cyc.y + xc.z * cyc.z + xc.w * cyc.w
                         + xd.x * cyd.x + xd.y * cyd.y + xd.z * cyd.z + xd.w * cyd.w;
                psq[q] = make_float4(s0, s1, s2, s3);
                sum += s0 + s1 + s2 + s3;
                sumsq += s0 * s0 + s1 * s1 + s2 * s2 + s3 * s3;
            }
            #pragma unroll
            for (int o = 32; o > 0; o >>= 1) {
                sum += __shfl_xor(sum, o);
                sumsq += __shfl_xor(sumsq, o);
            }
            float mu = sum * (1.0f / PS_DIM);
            float var = sumsq * (1.0f / PS_DIM) - mu * mu;
            float inv = rsqrtf(var + 1e-5f);

            float pacc = 0.0f;
            #pragma unroll
            for (int q = 0; q < 16; ++q) {
                int w = lane + 64 * q;
                float4 g = *(const float4*)(gamma + w * 4);
                float4 bt = *(const float4*)(beta + w * 4);
                float4 wp = *(const float4*)(Wps + w * 4);
                float z0 = (psq[q].x - mu) * inv;
                float z1 = (psq[q].y - mu) * inv;
                float z2 = (psq[q].z - mu) * inv;
                float z3 = (psq[q].w - mu) * inv;
                float v0 = z0 * g.x + bt.x;
                float v1 = z1 * g.y + bt.y;
                float v2 = z2 * g.z + bt.z;
                float v3 = z3 * g.w + bt.w;
                pacc += v0 * wp.x + v1 * wp.y + v2 * wp.z + v3 * wp.w;
                int x = w >> 5, yy = w & 31;
                if (x <= yy) {
                    int u = x * (65 - x) / 2 + (yy - x);
                    ((int*)ps_s8[wv])[u] = pk_fp8x4(z0, z1, z2, z3);
                }
            }
            #pragma unroll
            for (int o = 32; o > 0; o >>= 1) pacc += __shfl_down(pacc, o);
            if (lane == 0) psl[atom] = pacc;

            u8* rowp = psn + (size_t)atom * PS_K;
            #pragma unroll
            for (int cb = 0; cb < 3; ++cb) {
                int c = cb * 64 + lane;
                if (c < PS_K / 16) {   // 144 chunks
                    int gcs = (c & ~7) | ((c & 7) ^ (atom & 7));
                    *(uint4*)(rowp + (size_t)gcs * 16) =
                        *(const uint4*)(ps_s8[wv] + (size_t)c * 16);
                }
            }
        }
    }
}

// ------------------------------------------------- MX-fp8 MFMA GEMM1 (R1 structure)
// h1 = fp8(silu(invs*zhat@W1f^T + b1)). K = PS_K = 2304 (9 BK=256 steps).
__global__ __launch_bounds__(256) void gemm_f8_kernel(
    const u8* __restrict__ A, const u8* __restrict__ Bt,
    u8* __restrict__ H, const float* __restrict__ b1,
    int M, int Nc, int K, float invs)
{
    __shared__ __align__(16) char smem[65536];   // A: 128x256B = 32KB | B: 128x256B = 32KB
    int tid = threadIdx.x;
    int bm = blockIdx.x, bn = blockIdx.y;
    int wave = tid >> 6, lane = tid & 63;
    int wm = (wave >> 1) * 64, wn = (wave & 1) * 64;
    int lm = lane & 15, quad = lane >> 4;

    floatx4 acc[4][4] = {};
    const int rowA0 = bm * 128, rowB0 = bn * 128;
    const size_t stride = (size_t)K;
    const char* Ab = (const char*)A + (size_t)rowA0 * stride;
    const char* Bb = (const char*)Bt + (size_t)rowB0 * stride;
    const int sA = 0x7F7F7F7F, sB = 0x7F7F7F7F;

    for (int k0 = 0; k0 < K; k0 += 256) {
        #pragma unroll
        for (int s = 0; s < 8; ++s) {      // A: 2048 chunks (16 per 256B row)
            int L = s * 256 + tid;
            int row = L >> 4, boff = (L & 15) * 16;
            int lbase = (s * 256 + wave * 64) * 16;
            g2lds16(Ab + (size_t)row * stride + k0 + boff, smem + lbase);
        }
        #pragma unroll
        for (int s = 0; s < 8; ++s) {      // B: 2048 chunks
            int L = s * 256 + tid;
            int row = L >> 4, boff = (L & 15) * 16;
            int lbase = (s * 256 + wave * 64) * 16;
            g2lds16(Bb + (size_t)row * stride + k0 + boff, smem + 32768 + lbase);
        }
        __syncthreads();
        int key = lm & 7;
        int c0 = (2 * quad) ^ key, c1 = (2 * quad + 1) ^ key;
        #pragma unroll
        for (int h = 0; h < 2; ++h) {      // two 128B k-subsegments per barrier
            intx8 af[4], bfr[4];
            #pragma unroll
            for (int mi = 0; mi < 4; ++mi) {
                const char* base = smem + (wm + mi * 16 + lm) * 256 + h * 128;
                uint4 lo = *(const uint4*)(base + c0 * 16);
                uint4 hi = *(const uint4*)(base + c1 * 16);
                af[mi][0] = lo.x; af[mi][1] = lo.y; af[mi][2] = lo.z; af[mi][3] = lo.w;
                af[mi][4] = hi.x; af[mi][5] = hi.y; af[mi][6] = hi.z; af[mi][7] = hi.w;
            }
            #pragma unroll
            for (int ni = 0; ni < 4; ++ni) {
                const char* base = smem + 32768 + (wn + ni * 16 + lm) * 256 + h * 128;
                uint4 lo = *(const uint4*)(base + c0 * 16);
                uint4 hi = *(const uint4*)(base + c1 * 16);
                bfr[ni][0] = lo.x; bfr[ni][1] = lo.y; bfr[ni][2] = lo.z; bfr[ni][3] = lo.w;
                bfr[ni][4] = hi.x; bfr[ni][5] = hi.y; bfr[ni][6] = hi.z; bfr[ni][7] = hi.w;
            }
            #pragma unroll
            for (int mi = 0; mi < 4; ++mi)
                #pragma unroll
                for (int ni = 0; ni < 4; ++ni)
                    acc[mi][ni] = __builtin_amdgcn_mfma_scale_f32_16x16x128_f8f6f4(
                        af[mi], bfr[ni], acc[mi][ni], 0, 0, 0, sA, 0, sB);
        }
        __syncthreads();
    }

    u8* Cs8 = (u8*)smem;                 // 128 x 128 fp8 = 16KB
    #pragma unroll
    for (int mi = 0; mi < 4; ++mi)
        #pragma unroll
        for (int ni = 0; ni < 4; ++ni) {
            float bv = b1[bn * 128 + wn + ni * 16 + lm];
            #pragma unroll
            for (int r = 0; r < 4; ++r) {
                int row = wm + mi * 16 + quad * 4 + r;
                int col = wn + ni * 16 + lm;
                float v = acc[mi][ni][r] * invs + bv;
                v = v / (1.0f + __expf(-v));
                int pk = __builtin_amdgcn_cvt_pk_fp8_f32(v, 0.0f, 0, false);
                Cs8[row * 128 + col] = (u8)(pk & 0xFF);
            }
        }
    __syncthreads();
    #pragma unroll
    for (int c2 = 0; c2 < 4; ++c2) {
        int L = c2 * 256 + tid;          // 1024 chunks: row = L>>3, cc = L&7
        int row = L >> 3, cc = L & 7;
        int gcs = cc ^ (row & 7);        // rowA0 % 8 == 0
        *(uint4*)(H + (size_t)(rowA0 + row) * Nc + (size_t)(bn * 8 + gcs) * 16) =
            *(const uint4*)(Cs8 + (size_t)L * 16);
    }
}

// ------------------------------------------------- GEMM2 + final reduction
// Block (bm,bn) covers atoms [bm*128,(bm+1)*128) == batch bm exactly (N/B=128).
// Each block atomicAdds its silu()@W3 partial into out[bm]; the bn==0 block
// also folds in psl-sum and species-count@Wcomp. out[] zeroed by prep_kernel.
__global__ __launch_bounds__(256) void gemm2_fused_kernel(
    const u8* __restrict__ A, const u8* __restrict__ Bt,
    const float* __restrict__ W3, const float* __restrict__ psl,
    const int* __restrict__ numbers, const float* __restrict__ Wcomp,
    float* __restrict__ out, int Nc, int K, float invs)
{
    __shared__ __align__(16) char smem[65536];
    int tid = threadIdx.x;
    int bm = blockIdx.x, bn = blockIdx.y;
    int wave = tid >> 6, lane = tid & 63;
    int wm = (wave >> 1) * 64, wn = (wave & 1) * 64;
    int lm = lane & 15, quad = lane >> 4;

    floatx4 acc[4][4] = {};
    const int rowA0 = bm * 128, rowB0 = bn * 128;
    const size_t stride = (size_t)K;
    const char* Ab = (const char*)A + (size_t)rowA0 * stride;
    const char* Bb = (const char*)Bt + (size_t)rowB0 * stride;
    const int sA = 0x7F7F7F7F, sB = 0x7F7F7F7F;

    for (int k0 = 0; k0 < K; k0 += 256) {
        #pragma unroll
        for (int s = 0; s < 8; ++s) {
            int L = s * 256 + tid;
            int row = L >> 4, boff = (L & 15) * 16;
            int lbase = (s * 256 + wave * 64) * 16;
            g2lds16(Ab + (size_t)row * stride + k0 + boff, smem + lbase);
        }
        #pragma unroll
        for (int s = 0; s < 8; ++s) {
            int L = s * 256 + tid;
            int row = L >> 4, boff = (L & 15) * 16;
            int lbase = (s * 256 + wave * 64) * 16;
            g2lds16(Bb + (size_t)row * stride + k0 + boff, smem + 32768 + lbase);
        }
        __syncthreads();
        int key = lm & 7;
        int c0 = (2 * quad) ^ key, c1 = (2 * quad + 1) ^ key;
        #pragma unroll
        for (int h = 0; h < 2; ++h) {
            intx8 af[4], bfr[4];
            #pragma unroll
            for (int mi = 0; mi < 4; ++mi) {
                const char* base = smem + (wm + mi * 16 + lm) * 256 + h * 128;
                uint4 lo = *(const uint4*)(base + c0 * 16);
                uint4 hi = *(const uint4*)(base + c1 * 16);
                af[mi][0] = lo.x; af[mi][1] = lo.y; af[mi][2] = lo.z; af[mi][3] = lo.w;
                af[mi][4] = hi.x; af[mi][5] = hi.y; af[mi][6] = hi.z; af[mi][7] = hi.w;
            }
            #pragma unroll
            for (int ni = 0; ni < 4; ++ni) {
                const char* base = smem + 32768 + (wn + ni * 16 + lm) * 256 + h * 128;
                uint4 lo = *(const uint4*)(base + c0 * 16);
                uint4 hi = *(const uint4*)(base + c1 * 16);
                bfr[ni][0] = lo.x; bfr[ni][1] = lo.y; bfr[ni][2] = lo.z; bfr[ni][3] = lo.w;
                bfr[ni][4] = hi.x; bfr[ni][5] = hi.y; bfr[ni][6] = hi.z; bfr[ni][7] = hi.w;
            }
            #pragma unroll
            for (int mi = 0; mi < 4; ++mi)
                #pragma unroll
                for (int ni = 0; ni < 4; ++ni)
                    acc[mi][ni] = __builtin_amdgcn_mfma_scale_f32_16x16x128_f8f6f4(
                        af[mi], bfr[ni], acc[mi][ni], 0, 0, 0, sA, 0, sB);
        }
        __syncthreads();
    }

    // Epilogue: silu + W3 dot, wave reduce, block reduce, atomic into out[bm].
    float lt = 0.0f;
    #pragma unroll
    for (int ni = 0; ni < 4; ++ni) {
        float w3v = W3[bn * 128 + wn + ni * 16 + lm];
        #pragma unroll
        for (int mi = 0; mi < 4; ++mi)
            #pragma unroll
            for (int r = 0; r < 4; ++r) {
                float v = acc[mi][ni][r] * invs;
                v = v / (1.0f + __expf(-v));
                lt += v * w3v;
            }
    }
    #pragma unroll
    for (int o = 32; o > 0; o >>= 1) lt += __shfl_down(lt, o);
    float* wsum = (float*)smem;          // [0..3]
    int* c4 = ((int*)smem) + 8;          // [8..11]
    float* shp = ((float*)smem) + 12;    // [12..13]
    if (tid < S_SPEC) c4[tid] = 0;
    if (lane == 0) wsum[wave] = lt;
    __syncthreads();
    if (tid == 0)
        atomicAdd(&out[bm],
                  (wsum[0] + wsum[1] + wsum[2] + wsum[3]) * (1.0f / 128.0f));
    if (bn == 0) {
        if (tid < 128) {
            int a = bm * 128 + tid;
            float e = psl[a];
            atomicAdd(&c4[numbers[a]], 1);
            #pragma unroll
            for (int o = 32; o > 0; o >>= 1) e += __shfl_down(e, o);
            if ((tid & 63) == 0) shp[tid >> 6] = e;
        }
        __syncthreads();
        if (tid == 0) {
            float r = (shp[0] + shp[1]) * (1.0f / 128.0f);
            #pragma unroll
            for (int s = 0; s < S_SPEC; ++s) r += (float)c4[s] * Wcomp[s];
            atomicAdd(&out[bm], r);
        }
    }
}

extern "C" void kernel_launch(void* const* d_in, const int* in_sizes, int n_in,
                              void* d_out, int out_size, void* d_ws, size_t ws_size,
                              hipStream_t stream)
{
    const float* positions = (const float*)d_in[0];
    const float* cells     = (const float*)d_in[1];
    const int*   numbers   = (const int*)d_in[2];
    const int*   ei        = (const int*)d_in[3];
    const float* eo        = (const float*)d_in[4];
    const int*   batch     = (const int*)d_in[5];
    const float* gamma     = (const float*)d_in[6];
    const float* beta      = (const float*)d_in[7];
    const float* W_ps      = (const float*)d_in[8];
    const float* W1        = (const float*)d_in[9];
    const float* W2        = (const float*)d_in[10];
    const float* W3        = (const float*)d_in[11];
    const float* W_comp    = (const float*)d_in[12];
    float* out = (float*)d_out;

    char* ws = (char*)d_ws;
    float4* bucket = (float4*)ws;  ws += (size_t)N_ATOMS * S_SPEC * CAP4 * 16;  // 25.2 MB
    u8*    psn  = (u8*)ws;     ws += (size_t)N_ATOMS * PS_K;               // 18.9 MB
    u8*    h1   = (u8*)ws;     ws += (size_t)N_ATOMS * H1_DIM;             // 8 MB
    u8*    Wt1  = (u8*)ws;     ws += (size_t)H1_DIM * PS_K;                // 2.4 MB
    u8*    Wt2  = (u8*)ws;     ws += (size_t)H1_DIM * H1_DIM;              // 1 MB
    float* psl  = (float*)ws;  ws += (size_t)N_ATOMS * 4;
    int*   cnt  = (int*)ws;    ws += (size_t)N_ATOMS * S_SPEC * 4;         // 128 KB
    float* b1   = (float*)ws;  ws += (size_t)H1_DIM * 4;                   // 4 KB (adjacent to cnt!)

    // ONE memset covers cnt + b1 (contiguous)
    hipMemsetAsync(cnt, 0, (N_ATOMS * S_SPEC + H1_DIM) * sizeof(int), stream);

    prep_kernel<<<1024 + 104 * 32, 256, 0, stream>>>(
        positions, cells, numbers, ei, eo, batch, cnt, bucket,
        W1, gamma, beta, W2, Wt1, Wt2, b1, out);

    accum_ps_kernel<<<N_ATOMS / 4, 256, 0, stream>>>(
        bucket, cnt, gamma, beta, W_ps, psn, psl);

    gemm_f8_kernel<<<dim3(N_ATOMS / 128, H1_DIM / 128), 256, 0, stream>>>(
        psn, Wt1, h1, b1, N_ATOMS, H1_DIM, PS_K, 1.0f / 64.0f);

    gemm2_fused_kernel<<<dim3(N_ATOMS / 128, H1_DIM / 128), 256, 0, stream>>>(
        h1, Wt2, W3, psl, numbers, W_comp, out, H1_DIM, H1_DIM, 1.0f / 32.0f);
}

// Round 8
// 227.730 us; speedup vs baseline: 1.5169x; 1.5169x over previous
//
#include <hip/hip_runtime.h>
#include <hip/hip_bf16.h>
#include <math.h>

#define N_ATOMS 8192
#define B_BATCH 64
#define E_EDGES 262144
#define S_SPEC 4
#define NMAX 8
#define PS_DIM 4096
#define PS_K 2304            // folded upper-tri K: 528 pairs*4 lb = 2112, pad to 9*256
#define H1_DIM 1024
#define CAP4 48
#define CUTR 5.0f
#define PI_F 3.14159265358979f

typedef __bf16 bf16;
typedef unsigned long long u64;
typedef float floatx4 __attribute__((ext_vector_type(4)));
typedef int intx8 __attribute__((ext_vector_type(8)));
typedef unsigned char u8;

// async global->LDS, 16B per lane; LDS dest = wave-uniform base + lane*16
__device__ __forceinline__ void g2lds16(const void* g, void* l) {
    __builtin_amdgcn_global_load_lds(
        (const __attribute__((address_space(1))) void*)g,
        (__attribute__((address_space(3))) void*)l, 16, 0, 0);
}

__device__ __forceinline__ int pk_fp8x4(float a, float b, float c, float d) {
    int lo = __builtin_amdgcn_cvt_pk_fp8_f32(a, b, 0, false);
    return __builtin_amdgcn_cvt_pk_fp8_f32(c, d, lo, true);
}

__device__ __forceinline__ unsigned int bf16rne(float f) {
    unsigned int b = __float_as_uint(f);
    return (b + 0x7FFFu + ((b >> 16) & 1u)) >> 16;
}

// ------------------------------------------------- merged prep (1 dispatch):
// blocks [0,1024): edge scatter (block 0 also zeroes out[])
// blocks [1024,4352): W1 gamma-fold / W2 transpose
// block 4352: gw = gamma*Wps array + S2/S3 scalar reduction
__global__ __launch_bounds__(256) void prep_kernel(
    const float* __restrict__ pos, const float* __restrict__ cells,
    const int* __restrict__ numbers, const int* __restrict__ ei,
    const float* __restrict__ eo, const int* __restrict__ batch,
    int* __restrict__ cnt, float4* __restrict__ bucket,
    const float* __restrict__ W1, const float* __restrict__ gamma,
    const float* __restrict__ beta, const float* __restrict__ Wps,
    const float* __restrict__ W2,
    u8* __restrict__ Wt1, u8* __restrict__ Wt2, float* __restrict__ b1,
    float* __restrict__ gw, float* __restrict__ S23, float* __restrict__ out)
{
    if (blockIdx.x < 1024) {
        // ---------------- scatter ----------------
        if (blockIdx.x == 0 && threadIdx.x < B_BATCH) out[threadIdx.x] = 0.0f;
        int e = blockIdx.x * 256 + threadIdx.x;
        int i = ei[e];
        int j = ei[E_EDGES + e];
        int b = batch[i];
        const float* cell = cells + b * 9;
        float o0 = eo[e * 3 + 0], o1 = eo[e * 3 + 1], o2 = eo[e * 3 + 2];
        float rv[3];
        #pragma unroll
        for (int d = 0; d < 3; ++d) {
            float shift = o0 * cell[0 * 3 + d] + o1 * cell[1 * 3 + d] + o2 * cell[2 * 3 + d];
            rv[d] = pos[j * 3 + d] - pos[i * 3 + d] + shift;
        }
        float r2 = rv[0] * rv[0] + rv[1] * rv[1] + rv[2] * rv[2] + 1e-12f;
        if (r2 >= CUTR * CUTR) return;
        float r = sqrtf(r2);
        float a1 = r * (PI_F / CUTR);
        int sp = numbers[j];
        int q = i * S_SPEC + sp;
        int slot = atomicAdd(&cnt[q], 1);
        if (slot < CAP4)
            bucket[q * CAP4 + slot] = make_float4(rv[0], rv[1], rv[2], a1);
        return;
    }

    if (blockIdx.x == 4352) {
        // ---------------- gw + S2/S3 ----------------
        __shared__ float rs[8][2];
        int t = threadIdx.x, lane = t & 63, wv = t >> 6;
        float s2 = 0.0f, s3 = 0.0f;
        #pragma unroll
        for (int it = 0; it < 4; ++it) {
            int p4 = it * 256 + t;
            float4 g = *(const float4*)(gamma + p4 * 4);
            float4 bt = *(const float4*)(beta + p4 * 4);
            float4 w = *(const float4*)(Wps + p4 * 4);
            float4 gwv = make_float4(g.x * w.x, g.y * w.y, g.z * w.z, g.w * w.w);
            *(float4*)(gw + p4 * 4) = gwv;
            s2 += gwv.x + gwv.y + gwv.z + gwv.w;
            s3 += bt.x * w.x + bt.y * w.y + bt.z * w.z + bt.w * w.w;
        }
        #pragma unroll
        for (int o = 32; o > 0; o >>= 1) {
            s2 += __shfl_down(s2, o);
            s3 += __shfl_down(s3, o);
        }
        if (lane == 0) { rs[wv][0] = s2; rs[wv][1] = s3; }
        __syncthreads();
        if (t == 0) {
            S23[0] = rs[0][0] + rs[1][0] + rs[2][0] + rs[3][0];
            S23[1] = rs[0][1] + rs[1][1] + rs[2][1] + rs[3][1];
        }
        return;
    }

    // ---------------- weight prep ----------------
    __shared__ float tbuf[32][33];
    __shared__ float bred[8][32];
    int wid = blockIdx.x - 1024;
    int by = wid & 31;          // n-tile [0,32)
    int bx = wid >> 5;          // k-tile [0,104)
    int tx = threadIdx.x & 31, ty = threadIdx.x >> 5;
    int n0 = by * 32;

    if (bx < 72) {
        int k0 = bx * 32;
        float bacc = 0.0f;
        for (int r = 0; r < 32; r += 8) {
            int kk = ty + r;
            int kp = k0 + kk;
            int u = kp >> 2, lb = kp & 3;
            float val = 0.0f;
            if (u < 528) {
                int x = 0;
                while ((x + 1) * (64 - x) / 2 <= u) ++x;
                int y = x + (u - x * (65 - x) / 2);
                int p1 = x * 128 + y * 4 + lb;
                float w1v = W1[(size_t)p1 * H1_DIM + n0 + tx];
                val = gamma[p1] * w1v;
                bacc += beta[p1] * w1v;
                if (x < y) {
                    int p2 = y * 128 + x * 4 + lb;
                    float w2v = W1[(size_t)p2 * H1_DIM + n0 + tx];
                    val += gamma[p2] * w2v;
                    bacc += beta[p2] * w2v;
                }
            }
            tbuf[kk][tx] = val;
        }
        bred[ty][tx] = bacc;
        __syncthreads();
        if (ty == 0) {
            float s = 0.0f;
            #pragma unroll
            for (int i = 0; i < 8; ++i) s += bred[i][tx];
            atomicAdd(&b1[n0 + tx], s);
        }
        if (threadIdx.x < 64) {
            int nl = threadIdx.x >> 1, cc = threadIdx.x & 1;
            int n = n0 + nl;
            unsigned int w[4];
            #pragma unroll
            for (int g = 0; g < 4; ++g) {
                int kb = cc * 16 + g * 4;
                w[g] = (unsigned int)pk_fp8x4(
                    tbuf[kb + 0][nl] * 64.0f, tbuf[kb + 1][nl] * 64.0f,
                    tbuf[kb + 2][nl] * 64.0f, tbuf[kb + 3][nl] * 64.0f);
            }
            int gc = (k0 >> 4) + cc;
            int gcs = (gc & ~7) | ((gc & 7) ^ (n & 7));
            *(uint4*)(Wt1 + (size_t)n * PS_K + (size_t)gcs * 16) =
                make_uint4(w[0], w[1], w[2], w[3]);
        }
    } else {
        int k0 = (bx - 72) * 32;
        #pragma unroll
        for (int r = 0; r < 32; r += 8)
            tbuf[ty + r][tx] = W2[(size_t)(k0 + ty + r) * H1_DIM + n0 + tx];
        __syncthreads();
        if (threadIdx.x < 64) {
            int nl = threadIdx.x >> 1, cc = threadIdx.x & 1;
            int n = n0 + nl;
            unsigned int w[4];
            #pragma unroll
            for (int g = 0; g < 4; ++g) {
                int kb = cc * 16 + g * 4;
                w[g] = (unsigned int)pk_fp8x4(
                    tbuf[kb + 0][nl] * 32.0f, tbuf[kb + 1][nl] * 32.0f,
                    tbuf[kb + 2][nl] * 32.0f, tbuf[kb + 3][nl] * 32.0f);
            }
            int gc = (k0 >> 4) + cc;
            int gcs = (gc & ~7) | ((gc & 7) ^ (n & 7));
            *(uint4*)(Wt2 + (size_t)n * H1_DIM + (size_t)gcs * 16) =
                make_uint4(w[0], w[1], w[2], w[3]);
        }
    }
}

// ---------------------------------------------------------------- fused accum + PS/LN
// Wave-per-atom, zero barriers (R7 structure) with the VGPR fix: ps values
// spill to LDS as bf16x4 (psf, upper-tri only) instead of 64 VGPRs; psl via
// precomputed gw/S2/S3 algebra (one float4 load per q instead of three).
// __launch_bounds__(256,3) caps VGPR ~170 -> 3 waves/SIMD (1.5x R7).
__global__ __launch_bounds__(256, 3) void accum_ps_kernel(
    const float4* __restrict__ bucket, const int* __restrict__ cnt,
    const float* __restrict__ gw, const float* __restrict__ S23,
    u8* __restrict__ psn, float* __restrict__ psl)
{
    __shared__ __align__(16) float cl[4][32 * 20];   // 10240 B
    __shared__ __align__(16) u64 psf[4][528];        // 16896 B, bf16x4 per u

    int t = threadIdx.x;
    int wv = t >> 6, lane = t & 63;
    int atom = blockIdx.x * 4 + wv;

    // ---------------- Phase A (per-wave) ----------------
    {
        int sp_l = lane >> 4;
        int nidx = (lane >> 1) & 7;
        float nf = (float)(nidx + 1);
        int par = lane & 1;

        int myCnt = cnt[atom * S_SPEC + sp_l];
        if (myCnt > CAP4) myCnt = CAP4;
        int m1 = max(myCnt, __shfl_xor(myCnt, 16));
        int mx = max(m1, __shfl_xor(m1, 32));

        const float4* q = bucket + (size_t)(atom * S_SPEC + sp_l) * CAP4;
        float acc[8] = {};
        #pragma unroll 2
        for (int e = 0; e < mx; ++e) {
            float4 d = q[e];
            bool valid = e < myCnt;
            float a1 = d.w;
            float inv_r = (PI_F / CUTR) * __frcp_rn(a1);
            float fc = 0.5f * __cosf(a1) + 0.5f;
            float rn = fc * inv_r * __sinf(nf * a1);
            rn = valid ? rn : 0.0f;

            float x = d.x * inv_r, y = d.y * inv_r, z = d.z * inv_r;
            float x2 = x * x, y2 = y * y, z2 = z * z;
            float Ys[8];
            if (par == 0) {
                Ys[0] = 0.28209479f;
                Ys[1] = 0.48860251f * y;
                Ys[2] = 0.48860251f * z;
                Ys[3] = 0.48860251f * x;
                Ys[4] = 1.09254843f * x * y;
                Ys[5] = 1.09254843f * y * z;
                Ys[6] = 0.31539157f * (3.0f * z2 - 1.0f);
                Ys[7] = 1.09254843f * x * z;
            } else {
                Ys[0] = 0.54627422f * (x2 - y2);
                Ys[1] = 0.59004359f * y * (3.0f * x2 - y2);
                Ys[2] = 2.89061144f * x * y * z;
                Ys[3] = 0.45704579f * y * (5.0f * z2 - 1.0f);
                Ys[4] = 0.37317633f * z * (5.0f * z2 - 3.0f);
                Ys[5] = 0.45704579f * x * (5.0f * z2 - 1.0f);
                Ys[6] = 1.44530572f * z * (x2 - y2);
                Ys[7] = 0.59004359f * x * (x2 - 3.0f * y2);
            }
            #pragma unroll
            for (int k = 0; k < 8; ++k) acc[k] += rn * Ys[k];
        }
        int X = sp_l * 8 + nidx;
        float* dst = &cl[wv][X * 20 + par * 8];
        *(float4*)(dst + 0) = make_float4(acc[0], acc[1], acc[2], acc[3]);
        *(float4*)(dst + 4) = make_float4(acc[4], acc[5], acc[6], acc[7]);
    }
    // no barrier: same wave produces and consumes cl[wv] / psf[wv]

    // ---------------- Phase B pass 1: ps + stats + S1, spill bf16 to LDS ----
    const float* cl_x = cl[wv];
    int y = lane & 31;
    int xb = lane >> 5;
    float4 cya = *(const float4*)&cl_x[y * 20 + 0];
    float4 cyb = *(const float4*)&cl_x[y * 20 + 4];
    float4 cyc = *(const float4*)&cl_x[y * 20 + 8];
    float4 cyd = *(const float4*)&cl_x[y * 20 + 12];

    float sum = 0.0f, sumsq = 0.0f, S1 = 0.0f;
    #pragma unroll
    for (int q = 0; q < 16; ++q) {
        int x = xb + 2 * q;
        float4 xa = *(const float4*)&cl_x[x * 20 + 0];
        float4 xbv = *(const float4*)&cl_x[x * 20 + 4];
        float4 xc = *(const float4*)&cl_x[x * 20 + 8];
        float4 xd = *(const float4*)&cl_x[x * 20 + 12];
        float s0 = xa.x * cya.x;
        float s1 = xa.y * cya.y + xa.z * cya.z + xa.w * cya.w;
        float s2 = xbv.x * cyb.x + xbv.y * cyb.y + xbv.z * cyb.z + xbv.w * cyb.w
                 + xc.x * cyc.x;
        float s3 = xc.y * cyc.y + xc.z * cyc.z + xc.w * cyc.w
                 + xd.x * cyd.x + xd.y * cyd.y + xd.z * cyd.z + xd.w * cyd.w;
        sum += s0 + s1 + s2 + s3;
        sumsq += s0 * s0 + s1 * s1 + s2 * s2 + s3 * s3;
        int w = lane + 64 * q;
        float4 gwv = *(const float4*)(gw + w * 4);
        S1 += s0 * gwv.x + s1 * gwv.y + s2 * gwv.z + s3 * gwv.w;
        if (x <= y) {
            int u = x * (65 - x) / 2 + (y - x);
            u64 pk = (u64)(bf16rne(s0) | (bf16rne(s1) << 16))
                   | ((u64)(bf16rne(s2) | (bf16rne(s3) << 16)) << 32);
            psf[wv][u] = pk;
        }
    }
    #pragma unroll
    for (int o = 32; o > 0; o >>= 1) {
        sum += __shfl_xor(sum, o);
        sumsq += __shfl_xor(sumsq, o);
        S1 += __shfl_xor(S1, o);
    }
    float mu = sum * (1.0f / PS_DIM);
    float var = sumsq * (1.0f / PS_DIM) - mu * mu;
    float inv = rsqrtf(var + 1e-5f);
    if (lane == 0)
        psl[atom] = inv * (S1 - mu * S23[0]) + S23[1];

    // ---------------- Phase B pass 2: normalize, fp8-pack, direct store ----
    u8* rowp = psn + (size_t)atom * PS_K;
    #pragma unroll
    for (int it = 0; it < 3; ++it) {
        int c = it * 64 + lane;
        if (c < PS_K / 16) {             // 144 chunks
            uint4 outw = make_uint4(0, 0, 0, 0);
            if (c < 132) {               // u = 4c..4c+3 (528 = 4*132 pad boundary)
                unsigned int wds[4];
                #pragma unroll
                for (int j = 0; j < 4; ++j) {
                    u64 v = psf[wv][4 * c + j];
                    unsigned int lo = (unsigned int)v, hi = (unsigned int)(v >> 32);
                    float f0 = __uint_as_float(lo << 16);
                    float f1 = __uint_as_float(lo & 0xFFFF0000u);
                    float f2 = __uint_as_float(hi << 16);
                    float f3 = __uint_as_float(hi & 0xFFFF0000u);
                    wds[j] = (unsigned int)pk_fp8x4(
                        (f0 - mu) * inv, (f1 - mu) * inv,
                        (f2 - mu) * inv, (f3 - mu) * inv);
                }
                outw = make_uint4(wds[0], wds[1], wds[2], wds[3]);
            }
            int gcs = (c & ~7) | ((c & 7) ^ (atom & 7));
            *(uint4*)(rowp + (size_t)gcs * 16) = outw;
        }
    }
}

// ------------------------------------------------- MX-fp8 MFMA GEMM1 (R1 structure)
// h1 = fp8(silu(invs*zhat@W1f^T + b1)). K = PS_K = 2304 (9 BK=256 steps).
__global__ __launch_bounds__(256) void gemm_f8_kernel(
    const u8* __restrict__ A, const u8* __restrict__ Bt,
    u8* __restrict__ H, const float* __restrict__ b1,
    int M, int Nc, int K, float invs)
{
    __shared__ __align__(16) char smem[65536];   // A: 128x256B = 32KB | B: 128x256B = 32KB
    int tid = threadIdx.x;
    int bm = blockIdx.x, bn = blockIdx.y;
    int wave = tid >> 6, lane = tid & 63;
    int wm = (wave >> 1) * 64, wn = (wave & 1) * 64;
    int lm = lane & 15, quad = lane >> 4;

    floatx4 acc[4][4] = {};
    const int rowA0 = bm * 128, rowB0 = bn * 128;
    const size_t stride = (size_t)K;
    const char* Ab = (const char*)A + (size_t)rowA0 * stride;
    const char* Bb = (const char*)Bt + (size_t)rowB0 * stride;
    const int sA = 0x7F7F7F7F, sB = 0x7F7F7F7F;

    for (int k0 = 0; k0 < K; k0 += 256) {
        #pragma unroll
        for (int s = 0; s < 8; ++s) {      // A: 2048 chunks (16 per 256B row)
            int L = s * 256 + tid;
            int row = L >> 4, boff = (L & 15) * 16;
            int lbase = (s * 256 + wave * 64) * 16;
            g2lds16(Ab + (size_t)row * stride + k0 + boff, smem + lbase);
        }
        #pragma unroll
        for (int s = 0; s < 8; ++s) {      // B: 2048 chunks
            int L = s * 256 + tid;
            int row = L >> 4, boff = (L & 15) * 16;
            int lbase = (s * 256 + wave * 64) * 16;
            g2lds16(Bb + (size_t)row * stride + k0 + boff, smem + 32768 + lbase);
        }
        __syncthreads();
        int key = lm & 7;
        int c0 = (2 * quad) ^ key, c1 = (2 * quad + 1) ^ key;
        #pragma unroll
        for (int h = 0; h < 2; ++h) {      // two 128B k-subsegments per barrier
            intx8 af[4], bfr[4];
            #pragma unroll
            for (int mi = 0; mi < 4; ++mi) {
                const char* base = smem + (wm + mi * 16 + lm) * 256 + h * 128;
                uint4 lo = *(const uint4*)(base + c0 * 16);
                uint4 hi = *(const uint4*)(base + c1 * 16);
                af[mi][0] = lo.x; af[mi][1] = lo.y; af[mi][2] = lo.z; af[mi][3] = lo.w;
                af[mi][4] = hi.x; af[mi][5] = hi.y; af[mi][6] = hi.z; af[mi][7] = hi.w;
            }
            #pragma unroll
            for (int ni = 0; ni < 4; ++ni) {
                const char* base = smem + 32768 + (wn + ni * 16 + lm) * 256 + h * 128;
                uint4 lo = *(const uint4*)(base + c0 * 16);
                uint4 hi = *(const uint4*)(base + c1 * 16);
                bfr[ni][0] = lo.x; bfr[ni][1] = lo.y; bfr[ni][2] = lo.z; bfr[ni][3] = lo.w;
                bfr[ni][4] = hi.x; bfr[ni][5] = hi.y; bfr[ni][6] = hi.z; bfr[ni][7] = hi.w;
            }
            #pragma unroll
            for (int mi = 0; mi < 4; ++mi)
                #pragma unroll
                for (int ni = 0; ni < 4; ++ni)
                    acc[mi][ni] = __builtin_amdgcn_mfma_scale_f32_16x16x128_f8f6f4(
                        af[mi], bfr[ni], acc[mi][ni], 0, 0, 0, sA, 0, sB);
        }
        __syncthreads();
    }

    u8* Cs8 = (u8*)smem;                 // 128 x 128 fp8 = 16KB
    #pragma unroll
    for (int mi = 0; mi < 4; ++mi)
        #pragma unroll
        for (int ni = 0; ni < 4; ++ni) {
            float bv = b1[bn * 128 + wn + ni * 16 + lm];
            #pragma unroll
            for (int r = 0; r < 4; ++r) {
                int row = wm + mi * 16 + quad * 4 + r;
                int col = wn + ni * 16 + lm;
                float v = acc[mi][ni][r] * invs + bv;
                v = v / (1.0f + __expf(-v));
                int pk = __builtin_amdgcn_cvt_pk_fp8_f32(v, 0.0f, 0, false);
                Cs8[row * 128 + col] = (u8)(pk & 0xFF);
            }
        }
    __syncthreads();
    #pragma unroll
    for (int c2 = 0; c2 < 4; ++c2) {
        int L = c2 * 256 + tid;          // 1024 chunks: row = L>>3, cc = L&7
        int row = L >> 3, cc = L & 7;
        int gcs = cc ^ (row & 7);        // rowA0 % 8 == 0
        *(uint4*)(H + (size_t)(rowA0 + row) * Nc + (size_t)(bn * 8 + gcs) * 16) =
            *(const uint4*)(Cs8 + (size_t)L * 16);
    }
}

// ------------------------------------------------- GEMM2 + final reduction
__global__ __launch_bounds__(256) void gemm2_fused_kernel(
    const u8* __restrict__ A, const u8* __restrict__ Bt,
    const float* __restrict__ W3, const float* __restrict__ psl,
    const int* __restrict__ numbers, const float* __restrict__ Wcomp,
    float* __restrict__ out, int Nc, int K, float invs)
{
    __shared__ __align__(16) char smem[65536];
    int tid = threadIdx.x;
    int bm = blockIdx.x, bn = blockIdx.y;
    int wave = tid >> 6, lane = tid & 63;
    int wm = (wave >> 1) * 64, wn = (wave & 1) * 64;
    int lm = lane & 15, quad = lane >> 4;

    floatx4 acc[4][4] = {};
    const int rowA0 = bm * 128, rowB0 = bn * 128;
    const size_t stride = (size_t)K;
    const char* Ab = (const char*)A + (size_t)rowA0 * stride;
    const char* Bb = (const char*)Bt + (size_t)rowB0 * stride;
    const int sA = 0x7F7F7F7F, sB = 0x7F7F7F7F;

    for (int k0 = 0; k0 < K; k0 += 256) {
        #pragma unroll
        for (int s = 0; s < 8; ++s) {
            int L = s * 256 + tid;
            int row = L >> 4, boff = (L & 15) * 16;
            int lbase = (s * 256 + wave * 64) * 16;
            g2lds16(Ab + (size_t)row * stride + k0 + boff, smem + lbase);
        }
        #pragma unroll
        for (int s = 0; s < 8; ++s) {
            int L = s * 256 + tid;
            int row = L >> 4, boff = (L & 15) * 16;
            int lbase = (s * 256 + wave * 64) * 16;
            g2lds16(Bb + (size_t)row * stride + k0 + boff, smem + 32768 + lbase);
        }
        __syncthreads();
        int key = lm & 7;
        int c0 = (2 * quad) ^ key, c1 = (2 * quad + 1) ^ key;
        #pragma unroll
        for (int h = 0; h < 2; ++h) {
            intx8 af[4], bfr[4];
            #pragma unroll
            for (int mi = 0; mi < 4; ++mi) {
                const char* base = smem + (wm + mi * 16 + lm) * 256 + h * 128;
                uint4 lo = *(const uint4*)(base + c0 * 16);
                uint4 hi = *(const uint4*)(base + c1 * 16);
                af[mi][0] = lo.x; af[mi][1] = lo.y; af[mi][2] = lo.z; af[mi][3] = lo.w;
                af[mi][4] = hi.x; af[mi][5] = hi.y; af[mi][6] = hi.z; af[mi][7] = hi.w;
            }
            #pragma unroll
            for (int ni = 0; ni < 4; ++ni) {
                const char* base = smem + 32768 + (wn + ni * 16 + lm) * 256 + h * 128;
                uint4 lo = *(const uint4*)(base + c0 * 16);
                uint4 hi = *(const uint4*)(base + c1 * 16);
                bfr[ni][0] = lo.x; bfr[ni][1] = lo.y; bfr[ni][2] = lo.z; bfr[ni][3] = lo.w;
                bfr[ni][4] = hi.x; bfr[ni][5] = hi.y; bfr[ni][6] = hi.z; bfr[ni][7] = hi.w;
            }
            #pragma unroll
            for (int mi = 0; mi < 4; ++mi)
                #pragma unroll
                for (int ni = 0; ni < 4; ++ni)
                    acc[mi][ni] = __builtin_amdgcn_mfma_scale_f32_16x16x128_f8f6f4(
                        af[mi], bfr[ni], acc[mi][ni], 0, 0, 0, sA, 0, sB);
        }
        __syncthreads();
    }

    float lt = 0.0f;
    #pragma unroll
    for (int ni = 0; ni < 4; ++ni) {
        float w3v = W3[bn * 128 + wn + ni * 16 + lm];
        #pragma unroll
        for (int mi = 0; mi < 4; ++mi)
            #pragma unroll
            for (int r = 0; r < 4; ++r) {
                float v = acc[mi][ni][r] * invs;
                v = v / (1.0f + __expf(-v));
                lt += v * w3v;
            }
    }
    #pragma unroll
    for (int o = 32; o > 0; o >>= 1) lt += __shfl_down(lt, o);
    float* wsum = (float*)smem;          // [0..3]
    int* c4 = ((int*)smem) + 8;          // [8..11]
    float* shp = ((float*)smem) + 12;    // [12..13]
    if (tid < S_SPEC) c4[tid] = 0;
    if (lane == 0) wsum[wave] = lt;
    __syncthreads();
    if (tid == 0)
        atomicAdd(&out[bm],
                  (wsum[0] + wsum[1] + wsum[2] + wsum[3]) * (1.0f / 128.0f));
    if (bn == 0) {
        if (tid < 128) {
            int a = bm * 128 + tid;
            float e = psl[a];
            atomicAdd(&c4[numbers[a]], 1);
            #pragma unroll
            for (int o = 32; o > 0; o >>= 1) e += __shfl_down(e, o);
            if ((tid & 63) == 0) shp[tid >> 6] = e;
        }
        __syncthreads();
        if (tid == 0) {
            float r = (shp[0] + shp[1]) * (1.0f / 128.0f);
            #pragma unroll
            for (int s = 0; s < S_SPEC; ++s) r += (float)c4[s] * Wcomp[s];
            atomicAdd(&out[bm], r);
        }
    }
}

extern "C" void kernel_launch(void* const* d_in, const int* in_sizes, int n_in,
                              void* d_out, int out_size, void* d_ws, size_t ws_size,
                              hipStream_t stream)
{
    const float* positions = (const float*)d_in[0];
    const float* cells     = (const float*)d_in[1];
    const int*   numbers   = (const int*)d_in[2];
    const int*   ei        = (const int*)d_in[3];
    const float* eo        = (const float*)d_in[4];
    const int*   batch     = (const int*)d_in[5];
    const float* gamma     = (const float*)d_in[6];
    const float* beta      = (const float*)d_in[7];
    const float* W_ps      = (const float*)d_in[8];
    const float* W1        = (const float*)d_in[9];
    const float* W2        = (const float*)d_in[10];
    const float* W3        = (const float*)d_in[11];
    const float* W_comp    = (const float*)d_in[12];
    float* out = (float*)d_out;

    char* ws = (char*)d_ws;
    float4* bucket = (float4*)ws;  ws += (size_t)N_ATOMS * S_SPEC * CAP4 * 16;  // 25.2 MB
    u8*    psn  = (u8*)ws;     ws += (size_t)N_ATOMS * PS_K;               // 18.9 MB
    u8*    h1   = (u8*)ws;     ws += (size_t)N_ATOMS * H1_DIM;             // 8 MB
    u8*    Wt1  = (u8*)ws;     ws += (size_t)H1_DIM * PS_K;                // 2.4 MB
    u8*    Wt2  = (u8*)ws;     ws += (size_t)H1_DIM * H1_DIM;              // 1 MB
    float* psl  = (float*)ws;  ws += (size_t)N_ATOMS * 4;
    int*   cnt  = (int*)ws;    ws += (size_t)N_ATOMS * S_SPEC * 4;         // 128 KB
    float* b1   = (float*)ws;  ws += (size_t)H1_DIM * 4;                   // 4 KB (adjacent to cnt!)
    float* gw   = (float*)ws;  ws += (size_t)PS_DIM * 4;                   // 16 KB
    float* S23  = (float*)ws;  ws += 2 * 4;

    // ONE memset covers cnt + b1 (contiguous)
    hipMemsetAsync(cnt, 0, (N_ATOMS * S_SPEC + H1_DIM) * sizeof(int), stream);

    prep_kernel<<<4353, 256, 0, stream>>>(
        positions, cells, numbers, ei, eo, batch, cnt, bucket,
        W1, gamma, beta, W_ps, W2, Wt1, Wt2, b1, gw, S23, out);

    accum_ps_kernel<<<N_ATOMS / 4, 256, 0, stream>>>(
        bucket, cnt, gw, S23, psn, psl);

    gemm_f8_kernel<<<dim3(N_ATOMS / 128, H1_DIM / 128), 256, 0, stream>>>(
        psn, Wt1, h1, b1, N_ATOMS, H1_DIM, PS_K, 1.0f / 64.0f);

    gemm2_fused_kernel<<<dim3(N_ATOMS / 128, H1_DIM / 128), 256, 0, stream>>>(
        h1, Wt2, W3, psl, numbers, W_comp, out, H1_DIM, H1_DIM, 1.0f / 32.0f);
}

// Round 9
// 183.908 us; speedup vs baseline: 1.8783x; 1.2383x over previous
//
#include <hip/hip_runtime.h>
#include <hip/hip_bf16.h>
#include <math.h>

#define N_ATOMS 8192
#define B_BATCH 64
#define E_EDGES 262144
#define S_SPEC 4
#define NMAX 8
#define PS_DIM 4096
#define PS_K 2304            // folded upper-tri K: 528 pairs*4 lb = 2112, pad to 9*256
#define H1_DIM 1024
#define CAP4 48
#define CUTR 5.0f
#define PI_F 3.14159265358979f

typedef __bf16 bf16;
typedef unsigned long long u64;
typedef float floatx4 __attribute__((ext_vector_type(4)));
typedef int intx8 __attribute__((ext_vector_type(8)));
typedef unsigned char u8;

// async global->LDS, 16B per lane; LDS dest = wave-uniform base + lane*16
__device__ __forceinline__ void g2lds16(const void* g, void* l) {
    __builtin_amdgcn_global_load_lds(
        (const __attribute__((address_space(1))) void*)g,
        (__attribute__((address_space(3))) void*)l, 16, 0, 0);
}

__device__ __forceinline__ int pk_fp8x4(float a, float b, float c, float d) {
    int lo = __builtin_amdgcn_cvt_pk_fp8_f32(a, b, 0, false);
    return __builtin_amdgcn_cvt_pk_fp8_f32(c, d, lo, true);
}

// ------------------------------------------------- merged prep (1 dispatch):
// blocks [0,1024): edge scatter (block 0 also zeroes out[])
// blocks [1024,4352): W1 gamma-fold / W2 transpose
// block 4352: gw = gamma*Wps array + S2/S3 scalar reduction
__global__ __launch_bounds__(256) void prep_kernel(
    const float* __restrict__ pos, const float* __restrict__ cells,
    const int* __restrict__ numbers, const int* __restrict__ ei,
    const float* __restrict__ eo, const int* __restrict__ batch,
    int* __restrict__ cnt, float4* __restrict__ bucket,
    const float* __restrict__ W1, const float* __restrict__ gamma,
    const float* __restrict__ beta, const float* __restrict__ Wps,
    const float* __restrict__ W2,
    u8* __restrict__ Wt1, u8* __restrict__ Wt2, float* __restrict__ b1,
    float* __restrict__ gw, float* __restrict__ S23, float* __restrict__ out)
{
    if (blockIdx.x < 1024) {
        // ---------------- scatter ----------------
        if (blockIdx.x == 0 && threadIdx.x < B_BATCH) out[threadIdx.x] = 0.0f;
        int e = blockIdx.x * 256 + threadIdx.x;
        int i = ei[e];
        int j = ei[E_EDGES + e];
        int b = batch[i];
        const float* cell = cells + b * 9;
        float o0 = eo[e * 3 + 0], o1 = eo[e * 3 + 1], o2 = eo[e * 3 + 2];
        float rv[3];
        #pragma unroll
        for (int d = 0; d < 3; ++d) {
            float shift = o0 * cell[0 * 3 + d] + o1 * cell[1 * 3 + d] + o2 * cell[2 * 3 + d];
            rv[d] = pos[j * 3 + d] - pos[i * 3 + d] + shift;
        }
        float r2 = rv[0] * rv[0] + rv[1] * rv[1] + rv[2] * rv[2] + 1e-12f;
        if (r2 >= CUTR * CUTR) return;
        float r = sqrtf(r2);
        float a1 = r * (PI_F / CUTR);
        int sp = numbers[j];
        int q = i * S_SPEC + sp;
        int slot = atomicAdd(&cnt[q], 1);
        if (slot < CAP4)
            bucket[q * CAP4 + slot] = make_float4(rv[0], rv[1], rv[2], a1);
        return;
    }

    if (blockIdx.x == 4352) {
        // ---------------- gw + S2/S3 ----------------
        __shared__ float rs[8][2];
        int t = threadIdx.x, lane = t & 63, wv = t >> 6;
        float s2 = 0.0f, s3 = 0.0f;
        #pragma unroll
        for (int it = 0; it < 4; ++it) {
            int p4 = it * 256 + t;
            float4 g = *(const float4*)(gamma + p4 * 4);
            float4 bt = *(const float4*)(beta + p4 * 4);
            float4 w = *(const float4*)(Wps + p4 * 4);
            float4 gwv = make_float4(g.x * w.x, g.y * w.y, g.z * w.z, g.w * w.w);
            *(float4*)(gw + p4 * 4) = gwv;
            s2 += gwv.x + gwv.y + gwv.z + gwv.w;
            s3 += bt.x * w.x + bt.y * w.y + bt.z * w.z + bt.w * w.w;
        }
        #pragma unroll
        for (int o = 32; o > 0; o >>= 1) {
            s2 += __shfl_down(s2, o);
            s3 += __shfl_down(s3, o);
        }
        if (lane == 0) { rs[wv][0] = s2; rs[wv][1] = s3; }
        __syncthreads();
        if (t == 0) {
            S23[0] = rs[0][0] + rs[1][0] + rs[2][0] + rs[3][0];
            S23[1] = rs[0][1] + rs[1][1] + rs[2][1] + rs[3][1];
        }
        return;
    }

    // ---------------- weight prep ----------------
    __shared__ float tbuf[32][33];
    __shared__ float bred[8][32];
    int wid = blockIdx.x - 1024;
    int by = wid & 31;          // n-tile [0,32)
    int bx = wid >> 5;          // k-tile [0,104)
    int tx = threadIdx.x & 31, ty = threadIdx.x >> 5;
    int n0 = by * 32;

    if (bx < 72) {
        int k0 = bx * 32;
        float bacc = 0.0f;
        for (int r = 0; r < 32; r += 8) {
            int kk = ty + r;
            int kp = k0 + kk;
            int u = kp >> 2, lb = kp & 3;
            float val = 0.0f;
            if (u < 528) {
                int x = 0;
                while ((x + 1) * (64 - x) / 2 <= u) ++x;
                int y = x + (u - x * (65 - x) / 2);
                int p1 = x * 128 + y * 4 + lb;
                float w1v = W1[(size_t)p1 * H1_DIM + n0 + tx];
                val = gamma[p1] * w1v;
                bacc += beta[p1] * w1v;
                if (x < y) {
                    int p2 = y * 128 + x * 4 + lb;
                    float w2v = W1[(size_t)p2 * H1_DIM + n0 + tx];
                    val += gamma[p2] * w2v;
                    bacc += beta[p2] * w2v;
                }
            }
            tbuf[kk][tx] = val;
        }
        bred[ty][tx] = bacc;
        __syncthreads();
        if (ty == 0) {
            float s = 0.0f;
            #pragma unroll
            for (int i = 0; i < 8; ++i) s += bred[i][tx];
            atomicAdd(&b1[n0 + tx], s);
        }
        if (threadIdx.x < 64) {
            int nl = threadIdx.x >> 1, cc = threadIdx.x & 1;
            int n = n0 + nl;
            unsigned int w[4];
            #pragma unroll
            for (int g = 0; g < 4; ++g) {
                int kb = cc * 16 + g * 4;
                w[g] = (unsigned int)pk_fp8x4(
                    tbuf[kb + 0][nl] * 64.0f, tbuf[kb + 1][nl] * 64.0f,
                    tbuf[kb + 2][nl] * 64.0f, tbuf[kb + 3][nl] * 64.0f);
            }
            int gc = (k0 >> 4) + cc;
            int gcs = (gc & ~7) | ((gc & 7) ^ (n & 7));
            *(uint4*)(Wt1 + (size_t)n * PS_K + (size_t)gcs * 16) =
                make_uint4(w[0], w[1], w[2], w[3]);
        }
    } else {
        int k0 = (bx - 72) * 32;
        #pragma unroll
        for (int r = 0; r < 32; r += 8)
            tbuf[ty + r][tx] = W2[(size_t)(k0 + ty + r) * H1_DIM + n0 + tx];
        __syncthreads();
        if (threadIdx.x < 64) {
            int nl = threadIdx.x >> 1, cc = threadIdx.x & 1;
            int n = n0 + nl;
            unsigned int w[4];
            #pragma unroll
            for (int g = 0; g < 4; ++g) {
                int kb = cc * 16 + g * 4;
                w[g] = (unsigned int)pk_fp8x4(
                    tbuf[kb + 0][nl] * 32.0f, tbuf[kb + 1][nl] * 32.0f,
                    tbuf[kb + 2][nl] * 32.0f, tbuf[kb + 3][nl] * 32.0f);
            }
            int gc = (k0 >> 4) + cc;
            int gcs = (gc & ~7) | ((gc & 7) ^ (n & 7));
            *(uint4*)(Wt2 + (size_t)n * H1_DIM + (size_t)gcs * 16) =
                make_uint4(w[0], w[1], w[2], w[3]);
        }
    }
}

// ---------------------------------------------------------------- fused accum + PS/LN
// R6 block structure (proven 48us) + gw/S23 algebra: loop1 accumulates
// S1 = sum(ps * gamma*Wps) with ONE float4 load (gw) instead of loop2's
// three (gamma/beta/Wps); psl = inv*(S1 - mu*S2) + S3 computed by t0 right
// after the stats reduction (pacc tail + red2 + one barrier deleted).
__global__ __launch_bounds__(256) void accum_ps_kernel(
    const float4* __restrict__ bucket, const int* __restrict__ cnt,
    const float* __restrict__ gw, const float* __restrict__ S23,
    u8* __restrict__ psn, float* __restrict__ psl)
{
    __shared__ __align__(16) float cl[4][32 * 20];   // [atom][x*20+m], ld=20
    __shared__ __align__(16) u8 ps_s8[PS_K];
    __shared__ float red[12];

    int t = threadIdx.x;
    int wv = t >> 6, lane = t & 63;
    int atom0 = blockIdx.x * 4;

    // ---------------- Phase A ----------------
    {
        int atom = atom0 + wv;
        int sp_l = lane >> 4;
        int nidx = (lane >> 1) & 7;
        float nf = (float)(nidx + 1);
        int par = lane & 1;

        int myCnt = cnt[atom * S_SPEC + sp_l];
        if (myCnt > CAP4) myCnt = CAP4;
        int m1 = max(myCnt, __shfl_xor(myCnt, 16));
        int mx = max(m1, __shfl_xor(m1, 32));

        const float4* q = bucket + (size_t)(atom * S_SPEC + sp_l) * CAP4;
        float acc[8] = {};
        #pragma unroll 2
        for (int e = 0; e < mx; ++e) {
            float4 d = q[e];
            bool valid = e < myCnt;
            float a1 = d.w;
            float inv_r = (PI_F / CUTR) * __frcp_rn(a1);
            float fc = 0.5f * __cosf(a1) + 0.5f;
            float rn = fc * inv_r * __sinf(nf * a1);
            rn = valid ? rn : 0.0f;

            float x = d.x * inv_r, y = d.y * inv_r, z = d.z * inv_r;
            float x2 = x * x, y2 = y * y, z2 = z * z;
            float Ys[8];
            if (par == 0) {
                Ys[0] = 0.28209479f;
                Ys[1] = 0.48860251f * y;
                Ys[2] = 0.48860251f * z;
                Ys[3] = 0.48860251f * x;
                Ys[4] = 1.09254843f * x * y;
                Ys[5] = 1.09254843f * y * z;
                Ys[6] = 0.31539157f * (3.0f * z2 - 1.0f);
                Ys[7] = 1.09254843f * x * z;
            } else {
                Ys[0] = 0.54627422f * (x2 - y2);
                Ys[1] = 0.59004359f * y * (3.0f * x2 - y2);
                Ys[2] = 2.89061144f * x * y * z;
                Ys[3] = 0.45704579f * y * (5.0f * z2 - 1.0f);
                Ys[4] = 0.37317633f * z * (5.0f * z2 - 3.0f);
                Ys[5] = 0.45704579f * x * (5.0f * z2 - 1.0f);
                Ys[6] = 1.44530572f * z * (x2 - y2);
                Ys[7] = 0.59004359f * x * (x2 - 3.0f * y2);
            }
            #pragma unroll
            for (int k = 0; k < 8; ++k) acc[k] += rn * Ys[k];
        }
        int X = sp_l * 8 + nidx;
        float* dst = &cl[wv][X * 20 + par * 8];
        *(float4*)(dst + 0) = make_float4(acc[0], acc[1], acc[2], acc[3]);
        *(float4*)(dst + 4) = make_float4(acc[4], acc[5], acc[6], acc[7]);
    }
    if (t < 48) ((int*)ps_s8)[528 + t] = 0;   // zero the K-pad words once
    __syncthreads();

    float S2c = S23[0], S3c = S23[1];

    // ---------------- Phase B ----------------
    for (int a = 0; a < 4; ++a) {
        int atom = atom0 + a;
        const float* cl_x = cl[a];

        int y = t & 31;
        int xb = t >> 5;
        float4 cya = *(const float4*)&cl_x[y * 20 + 0];
        float4 cyb = *(const float4*)&cl_x[y * 20 + 4];
        float4 cyc = *(const float4*)&cl_x[y * 20 + 8];
        float4 cyd = *(const float4*)&cl_x[y * 20 + 12];

        float ps[4][4];
        float sum = 0.0f, sumsq = 0.0f, S1 = 0.0f;
        #pragma unroll
        for (int q = 0; q < 4; ++q) {
            int x = xb + 8 * q;
            float4 xa = *(const float4*)&cl_x[x * 20 + 0];
            float4 xbv = *(const float4*)&cl_x[x * 20 + 4];
            float4 xc = *(const float4*)&cl_x[x * 20 + 8];
            float4 xd = *(const float4*)&cl_x[x * 20 + 12];
            float s0 = xa.x * cya.x;
            float s1 = xa.y * cya.y + xa.z * cya.z + xa.w * cya.w;
            float s2 = xbv.x * cyb.x + xbv.y * cyb.y + xbv.z * cyb.z + xbv.w * cyb.w
                     + xc.x * cyc.x;
            float s3 = xc.y * cyc.y + xc.z * cyc.z + xc.w * cyc.w
                     + xd.x * cyd.x + xd.y * cyd.y + xd.z * cyd.z + xd.w * cyd.w;
            ps[q][0] = s0; ps[q][1] = s1; ps[q][2] = s2; ps[q][3] = s3;
            sum += s0 + s1 + s2 + s3;
            sumsq += s0 * s0 + s1 * s1 + s2 * s2 + s3 * s3;
            int p = t + 256 * q;
            float4 gwv = *(const float4*)(gw + p * 4);
            S1 += s0 * gwv.x + s1 * gwv.y + s2 * gwv.z + s3 * gwv.w;
        }
        #pragma unroll
        for (int o = 32; o > 0; o >>= 1) {
            sum += __shfl_down(sum, o);
            sumsq += __shfl_down(sumsq, o);
            S1 += __shfl_down(S1, o);
        }
        if ((t & 63) == 0) { red[wv] = sum; red[4 + wv] = sumsq; red[8 + wv] = S1; }
        __syncthreads();
        float tot = red[0] + red[1] + red[2] + red[3];
        float totsq = red[4] + red[5] + red[6] + red[7];
        float S1t = red[8] + red[9] + red[10] + red[11];
        float mu = tot * (1.0f / PS_DIM);
        float var = totsq * (1.0f / PS_DIM) - mu * mu;
        float inv = rsqrtf(var + 1e-5f);
        if (t == 0) psl[atom] = inv * (S1t - mu * S2c) + S3c;

        #pragma unroll
        for (int q = 0; q < 4; ++q) {
            int p = t + 256 * q;
            float z0 = (ps[q][0] - mu) * inv;
            float z1 = (ps[q][1] - mu) * inv;
            float z2 = (ps[q][2] - mu) * inv;
            float z3 = (ps[q][3] - mu) * inv;
            int x = p >> 5, yy = p & 31;
            if (x <= yy) {
                int u = x * (65 - x) / 2 + (yy - x);
                ((int*)ps_s8)[u] = pk_fp8x4(z0, z1, z2, z3);
            }
        }
        __syncthreads();
        u8* rowp = psn + (size_t)atom * PS_K;
        if (t < PS_K / 16) {   // 144 chunks
            int gcs = (t & ~7) | ((t & 7) ^ (atom & 7));
            *(uint4*)(rowp + (size_t)gcs * 16) = *(const uint4*)(ps_s8 + (size_t)t * 16);
        }
    }
}

// ------------------------------------------------- MX-fp8 MFMA GEMM1 (R1 structure)
// h1 = fp8(silu(invs*zhat@W1f^T + b1)). K = PS_K = 2304 (9 BK=256 steps).
__global__ __launch_bounds__(256) void gemm_f8_kernel(
    const u8* __restrict__ A, const u8* __restrict__ Bt,
    u8* __restrict__ H, const float* __restrict__ b1,
    int M, int Nc, int K, float invs)
{
    __shared__ __align__(16) char smem[65536];   // A: 128x256B = 32KB | B: 128x256B = 32KB
    int tid = threadIdx.x;
    int bm = blockIdx.x, bn = blockIdx.y;
    int wave = tid >> 6, lane = tid & 63;
    int wm = (wave >> 1) * 64, wn = (wave & 1) * 64;
    int lm = lane & 15, quad = lane >> 4;

    floatx4 acc[4][4] = {};
    const int rowA0 = bm * 128, rowB0 = bn * 128;
    const size_t stride = (size_t)K;
    const char* Ab = (const char*)A + (size_t)rowA0 * stride;
    const char* Bb = (const char*)Bt + (size_t)rowB0 * stride;
    const int sA = 0x7F7F7F7F, sB = 0x7F7F7F7F;

    for (int k0 = 0; k0 < K; k0 += 256) {
        #pragma unroll
        for (int s = 0; s < 8; ++s) {      // A: 2048 chunks (16 per 256B row)
            int L = s * 256 + tid;
            int row = L >> 4, boff = (L & 15) * 16;
            int lbase = (s * 256 + wave * 64) * 16;
            g2lds16(Ab + (size_t)row * stride + k0 + boff, smem + lbase);
        }
        #pragma unroll
        for (int s = 0; s < 8; ++s) {      // B: 2048 chunks
            int L = s * 256 + tid;
            int row = L >> 4, boff = (L & 15) * 16;
            int lbase = (s * 256 + wave * 64) * 16;
            g2lds16(Bb + (size_t)row * stride + k0 + boff, smem + 32768 + lbase);
        }
        __syncthreads();
        int key = lm & 7;
        int c0 = (2 * quad) ^ key, c1 = (2 * quad + 1) ^ key;
        #pragma unroll
        for (int h = 0; h < 2; ++h) {      // two 128B k-subsegments per barrier
            intx8 af[4], bfr[4];
            #pragma unroll
            for (int mi = 0; mi < 4; ++mi) {
                const char* base = smem + (wm + mi * 16 + lm) * 256 + h * 128;
                uint4 lo = *(const uint4*)(base + c0 * 16);
                uint4 hi = *(const uint4*)(base + c1 * 16);
                af[mi][0] = lo.x; af[mi][1] = lo.y; af[mi][2] = lo.z; af[mi][3] = lo.w;
                af[mi][4] = hi.x; af[mi][5] = hi.y; af[mi][6] = hi.z; af[mi][7] = hi.w;
            }
            #pragma unroll
            for (int ni = 0; ni < 4; ++ni) {
                const char* base = smem + 32768 + (wn + ni * 16 + lm) * 256 + h * 128;
                uint4 lo = *(const uint4*)(base + c0 * 16);
                uint4 hi = *(const uint4*)(base + c1 * 16);
                bfr[ni][0] = lo.x; bfr[ni][1] = lo.y; bfr[ni][2] = lo.z; bfr[ni][3] = lo.w;
                bfr[ni][4] = hi.x; bfr[ni][5] = hi.y; bfr[ni][6] = hi.z; bfr[ni][7] = hi.w;
            }
            #pragma unroll
            for (int mi = 0; mi < 4; ++mi)
                #pragma unroll
                for (int ni = 0; ni < 4; ++ni)
                    acc[mi][ni] = __builtin_amdgcn_mfma_scale_f32_16x16x128_f8f6f4(
                        af[mi], bfr[ni], acc[mi][ni], 0, 0, 0, sA, 0, sB);
        }
        __syncthreads();
    }

    u8* Cs8 = (u8*)smem;                 // 128 x 128 fp8 = 16KB
    #pragma unroll
    for (int mi = 0; mi < 4; ++mi)
        #pragma unroll
        for (int ni = 0; ni < 4; ++ni) {
            float bv = b1[bn * 128 + wn + ni * 16 + lm];
            #pragma unroll
            for (int r = 0; r < 4; ++r) {
                int row = wm + mi * 16 + quad * 4 + r;
                int col = wn + ni * 16 + lm;
                float v = acc[mi][ni][r] * invs + bv;
                v = v / (1.0f + __expf(-v));
                int pk = __builtin_amdgcn_cvt_pk_fp8_f32(v, 0.0f, 0, false);
                Cs8[row * 128 + col] = (u8)(pk & 0xFF);
            }
        }
    __syncthreads();
    #pragma unroll
    for (int c2 = 0; c2 < 4; ++c2) {
        int L = c2 * 256 + tid;          // 1024 chunks: row = L>>3, cc = L&7
        int row = L >> 3, cc = L & 7;
        int gcs = cc ^ (row & 7);        // rowA0 % 8 == 0
        *(uint4*)(H + (size_t)(rowA0 + row) * Nc + (size_t)(bn * 8 + gcs) * 16) =
            *(const uint4*)(Cs8 + (size_t)L * 16);
    }
}

// ------------------------------------------------- GEMM2 + final reduction
__global__ __launch_bounds__(256) void gemm2_fused_kernel(
    const u8* __restrict__ A, const u8* __restrict__ Bt,
    const float* __restrict__ W3, const float* __restrict__ psl,
    const int* __restrict__ numbers, const float* __restrict__ Wcomp,
    float* __restrict__ out, int Nc, int K, float invs)
{
    __shared__ __align__(16) char smem[65536];
    int tid = threadIdx.x;
    int bm = blockIdx.x, bn = blockIdx.y;
    int wave = tid >> 6, lane = tid & 63;
    int wm = (wave >> 1) * 64, wn = (wave & 1) * 64;
    int lm = lane & 15, quad = lane >> 4;

    floatx4 acc[4][4] = {};
    const int rowA0 = bm * 128, rowB0 = bn * 128;
    const size_t stride = (size_t)K;
    const char* Ab = (const char*)A + (size_t)rowA0 * stride;
    const char* Bb = (const char*)Bt + (size_t)rowB0 * stride;
    const int sA = 0x7F7F7F7F, sB = 0x7F7F7F7F;

    for (int k0 = 0; k0 < K; k0 += 256) {
        #pragma unroll
        for (int s = 0; s < 8; ++s) {
            int L = s * 256 + tid;
            int row = L >> 4, boff = (L & 15) * 16;
            int lbase = (s * 256 + wave * 64) * 16;
            g2lds16(Ab + (size_t)row * stride + k0 + boff, smem + lbase);
        }
        #pragma unroll
        for (int s = 0; s < 8; ++s) {
            int L = s * 256 + tid;
            int row = L >> 4, boff = (L & 15) * 16;
            int lbase = (s * 256 + wave * 64) * 16;
            g2lds16(Bb + (size_t)row * stride + k0 + boff, smem + 32768 + lbase);
        }
        __syncthreads();
        int key = lm & 7;
        int c0 = (2 * quad) ^ key, c1 = (2 * quad + 1) ^ key;
        #pragma unroll
        for (int h = 0; h < 2; ++h) {
            intx8 af[4], bfr[4];
            #pragma unroll
            for (int mi = 0; mi < 4; ++mi) {
                const char* base = smem + (wm + mi * 16 + lm) * 256 + h * 128;
                uint4 lo = *(const uint4*)(base + c0 * 16);
                uint4 hi = *(const uint4*)(base + c1 * 16);
                af[mi][0] = lo.x; af[mi][1] = lo.y; af[mi][2] = lo.z; af[mi][3] = lo.w;
                af[mi][4] = hi.x; af[mi][5] = hi.y; af[mi][6] = hi.z; af[mi][7] = hi.w;
            }
            #pragma unroll
            for (int ni = 0; ni < 4; ++ni) {
                const char* base = smem + 32768 + (wn + ni * 16 + lm) * 256 + h * 128;
                uint4 lo = *(const uint4*)(base + c0 * 16);
                uint4 hi = *(const uint4*)(base + c1 * 16);
                bfr[ni][0] = lo.x; bfr[ni][1] = lo.y; bfr[ni][2] = lo.z; bfr[ni][3] = lo.w;
                bfr[ni][4] = hi.x; bfr[ni][5] = hi.y; bfr[ni][6] = hi.z; bfr[ni][7] = hi.w;
            }
            #pragma unroll
            for (int mi = 0; mi < 4; ++mi)
                #pragma unroll
                for (int ni = 0; ni < 4; ++ni)
                    acc[mi][ni] = __builtin_amdgcn_mfma_scale_f32_16x16x128_f8f6f4(
                        af[mi], bfr[ni], acc[mi][ni], 0, 0, 0, sA, 0, sB);
        }
        __syncthreads();
    }

    float lt = 0.0f;
    #pragma unroll
    for (int ni = 0; ni < 4; ++ni) {
        float w3v = W3[bn * 128 + wn + ni * 16 + lm];
        #pragma unroll
        for (int mi = 0; mi < 4; ++mi)
            #pragma unroll
            for (int r = 0; r < 4; ++r) {
                float v = acc[mi][ni][r] * invs;
                v = v / (1.0f + __expf(-v));
                lt += v * w3v;
            }
    }
    #pragma unroll
    for (int o = 32; o > 0; o >>= 1) lt += __shfl_down(lt, o);
    float* wsum = (float*)smem;          // [0..3]
    int* c4 = ((int*)smem) + 8;          // [8..11]
    float* shp = ((float*)smem) + 12;    // [12..13]
    if (tid < S_SPEC) c4[tid] = 0;
    if (lane == 0) wsum[wave] = lt;
    __syncthreads();
    if (tid == 0)
        atomicAdd(&out[bm],
                  (wsum[0] + wsum[1] + wsum[2] + wsum[3]) * (1.0f / 128.0f));
    if (bn == 0) {
        if (tid < 128) {
            int a = bm * 128 + tid;
            float e = psl[a];
            atomicAdd(&c4[numbers[a]], 1);
            #pragma unroll
            for (int o = 32; o > 0; o >>= 1) e += __shfl_down(e, o);
            if ((tid & 63) == 0) shp[tid >> 6] = e;
        }
        __syncthreads();
        if (tid == 0) {
            float r = (shp[0] + shp[1]) * (1.0f / 128.0f);
            #pragma unroll
            for (int s = 0; s < S_SPEC; ++s) r += (float)c4[s] * Wcomp[s];
            atomicAdd(&out[bm], r);
        }
    }
}

extern "C" void kernel_launch(void* const* d_in, const int* in_sizes, int n_in,
                              void* d_out, int out_size, void* d_ws, size_t ws_size,
                              hipStream_t stream)
{
    const float* positions = (const float*)d_in[0];
    const float* cells     = (const float*)d_in[1];
    const int*   numbers   = (const int*)d_in[2];
    const int*   ei        = (const int*)d_in[3];
    const float* eo        = (const float*)d_in[4];
    const int*   batch     = (const int*)d_in[5];
    const float* gamma     = (const float*)d_in[6];
    const float* beta      = (const float*)d_in[7];
    const float* W_ps      = (const float*)d_in[8];
    const float* W1        = (const float*)d_in[9];
    const float* W2        = (const float*)d_in[10];
    const float* W3        = (const float*)d_in[11];
    const float* W_comp    = (const float*)d_in[12];
    float* out = (float*)d_out;

    char* ws = (char*)d_ws;
    float4* bucket = (float4*)ws;  ws += (size_t)N_ATOMS * S_SPEC * CAP4 * 16;  // 25.2 MB
    u8*    psn  = (u8*)ws;     ws += (size_t)N_ATOMS * PS_K;               // 18.9 MB
    u8*    h1   = (u8*)ws;     ws += (size_t)N_ATOMS * H1_DIM;             // 8 MB
    u8*    Wt1  = (u8*)ws;     ws += (size_t)H1_DIM * PS_K;                // 2.4 MB
    u8*    Wt2  = (u8*)ws;     ws += (size_t)H1_DIM * H1_DIM;              // 1 MB
    float* psl  = (float*)ws;  ws += (size_t)N_ATOMS * 4;
    int*   cnt  = (int*)ws;    ws += (size_t)N_ATOMS * S_SPEC * 4;         // 128 KB
    float* b1   = (float*)ws;  ws += (size_t)H1_DIM * 4;                   // 4 KB (adjacent to cnt!)
    float* gw   = (float*)ws;  ws += (size_t)PS_DIM * 4;                   // 16 KB
    float* S23  = (float*)ws;  ws += 2 * 4;

    // ONE memset covers cnt + b1 (contiguous)
    hipMemsetAsync(cnt, 0, (N_ATOMS * S_SPEC + H1_DIM) * sizeof(int), stream);

    prep_kernel<<<4353, 256, 0, stream>>>(
        positions, cells, numbers, ei, eo, batch, cnt, bucket,
        W1, gamma, beta, W_ps, W2, Wt1, Wt2, b1, gw, S23, out);

    accum_ps_kernel<<<N_ATOMS / 4, 256, 0, stream>>>(
        bucket, cnt, gw, S23, psn, psl);

    gemm_f8_kernel<<<dim3(N_ATOMS / 128, H1_DIM / 128), 256, 0, stream>>>(
        psn, Wt1, h1, b1, N_ATOMS, H1_DIM, PS_K, 1.0f / 64.0f);

    gemm2_fused_kernel<<<dim3(N_ATOMS / 128, H1_DIM / 128), 256, 0, stream>>>(
        h1, Wt2, W3, psl, numbers, W_comp, out, H1_DIM, H1_DIM, 1.0f / 32.0f);
}